// Round 4
// baseline (16980.347 us; speedup 1.0000x reference)
//
#include <hip/hip_runtime.h>
#include <math.h>
#include <float.h>
#include <limits.h>

#define B_ 8
#define C_ 32
#define N_ 4096
#define K_ 16
#define M_ 20   // per-chunk fp32 candidate margin (>=16)
#define QB 64   // queries per kB block
#define NCH 4   // j-chunks per block
#define TJ 32   // neighbor tile points

// ------------------------------------------------------------------
// ws layout:
//   yT  : [B][N][96] float   3,145,728 f
//   sq  : [B][N]     float      32,768 f
//   knn : [B][N][16] int       524,288 i
//   sqd : [B][N]     double     32,768 d  (8B-aligned)
//   Ek  : [32][64]   float       2,048 f
//   Ev  : [32][64]   float       2,048 f
//   Eq  : [32][32]   float       1,024 f
// ------------------------------------------------------------------

__global__ __launch_bounds__(256) void kE_combine(
    const float* __restrict__ Wk, const float* __restrict__ Dk,
    const float* __restrict__ Wv, const float* __restrict__ Dv,
    const float* __restrict__ Wq, const float* __restrict__ Dq,
    float* __restrict__ Ek, float* __restrict__ Ev, float* __restrict__ Eq) {
  int t = threadIdx.x;
  for (int e = t; e < 2048; e += 256) {
    int o = e >> 6, c = e & 63;
    float a = 0.f, v = 0.f;
    for (int m = 0; m < 32; ++m) {
      a = fmaf(Dk[o * 32 + m], Wk[m * 64 + c], a);
      v = fmaf(Dv[o * 32 + m], Wv[m * 64 + c], v);
    }
    Ek[e] = a; Ev[e] = v;
  }
  for (int e = t; e < 1024; e += 256) {
    int o = e >> 5, c = e & 31;
    float a = 0.f;
    for (int m = 0; m < 32; ++m) a = fmaf(Dq[o * 32 + m], Wq[m * 32 + c], a);
    Eq[e] = a;
  }
}

// transpose y [B][96][N] -> yT [B][N][96]; sq (fp32) and sqd (fp64)
__global__ __launch_bounds__(256) void kA_transpose(
    const float* __restrict__ y, float* __restrict__ yT,
    float* __restrict__ sq, double* __restrict__ sqd) {
  __shared__ float tile[96][65];
  int b = blockIdx.x >> 6;
  int n0 = (blockIdx.x & 63) * 64;
  int t = threadIdx.x;
  int g = t >> 6, ln = t & 63;
  #pragma unroll
  for (int r = 0; r < 24; ++r) {
    int d = g * 24 + r;
    tile[d][ln] = y[((size_t)b * 96 + d) * N_ + n0 + ln];
  }
  __syncthreads();
  if (t < 64) {
    float s = 0.f; double sd = 0.0;
    #pragma unroll
    for (int d = 0; d < 96; ++d) {
      float v = tile[d][t];
      s = fmaf(v, v, s);
      sd += (double)v * (double)v;
    }
    sq[b * N_ + n0 + t] = s;
    sqd[b * N_ + n0 + t] = sd;
  }
  for (int idx = t; idx < 64 * 96; idx += 256) {
    int nl = idx / 96, d = idx % 96;
    yT[((size_t)b * N_ + n0 + nl) * 96 + d] = tile[d][nl];
  }
}

// kNN, all-LDS scan. Block = 256 threads = 64 queries x 4 j-chunks.
// Queries live in LDS (sQ2, float2-strided). Neighbor tiles (32 pts)
// double-buffered in LDS, read as wave-broadcast b128. Per thread:
// 8 j's per tile, 1024 j's total. Registers stay ~110 (no spills).
// Pass 1: fp32 per-thread top-20. Pass 2: fp64 exact re-score -> sorted
// top-16. Merge: 64 threads do exact 4-way merge (scalar pointers).
__global__ __launch_bounds__(256) void kB_knn(
    const float* __restrict__ yT, const float* __restrict__ sq,
    const double* __restrict__ sqd, int* __restrict__ knn) {
  // union:  scan: sQ2 [48][64] f2 (24,576 B) | pt [2][768] f4 (24,576 B)
  //         merge: mvd [4][64][17] dbl (34,816 B) | mi [4][64][17] int (17,408 B)
  __shared__ __align__(16) char smem[52224];
  float2* sQ2 = (float2*)smem;                         // [48][64]
  float4* pt4 = (float4*)(smem + 24576);               // [2][768]
  double (*mvd)[QB][17] = (double(*)[QB][17])smem;     // [4][64][17]
  int    (*mi)[QB][17]  = (int(*)[QB][17])(smem + 34816);

  int t = threadIdx.x;
  int ql = t & 63, ch = t >> 6;       // wave-uniform ch
  int b = blockIdx.x >> 6;            // 64 blocks per batch
  int n0 = (blockIdx.x & 63) * QB;
  int qn = n0 + ql;

  const float* base = yT + (size_t)b * N_ * 96;
  const float* sqb = sq + b * N_;
  float sqi = sq[b * N_ + qn];

  // stage queries into LDS: sQ2[p][ql] = pair p of query ql
  for (int idx = t; idx < 48 * QB; idx += 256) {
    int p = idx >> 6, q2 = idx & 63;
    sQ2[idx] = ((const float2*)(base + (size_t)(n0 + q2) * 96))[p];
  }
  // stage tile 0
  {
    const float4* g = (const float4*)base;
    pt4[t] = g[t]; pt4[t + 256] = g[t + 256]; pt4[t + 512] = g[t + 512];
  }
  __syncthreads();

  float vals[M_]; int idxs[M_];
  #pragma unroll
  for (int i = 0; i < M_; ++i) { vals[i] = -FLT_MAX; idxs[i] = 0; }

  for (int tile = 0; tile < 128; ++tile) {
    int cb = tile & 1;
    float4 st0, st1, st2;
    bool have = (tile + 1) < 128;
    if (have) {
      const float4* g = (const float4*)(base + (size_t)(tile + 1) * TJ * 96);
      st0 = g[t]; st1 = g[t + 256]; st2 = g[t + 512];
    }
    float acc[8];
    #pragma unroll
    for (int jj = 0; jj < 8; ++jj) acc[jj] = 0.f;
    const float4* pr = pt4 + cb * 768 + (ch * 8) * 24;
    #pragma unroll
    for (int m = 0; m < 24; ++m) {
      float2 qa = sQ2[(2 * m) * 64 + ql];
      float2 qb = sQ2[(2 * m + 1) * 64 + ql];
      #pragma unroll
      for (int jj = 0; jj < 8; ++jj) {
        float4 p = pr[jj * 24 + m];
        acc[jj] = fmaf(qa.x, p.x,
                  fmaf(qa.y, p.y,
                  fmaf(qb.x, p.z,
                  fmaf(qb.y, p.w, acc[jj]))));
      }
    }
    #pragma unroll
    for (int jj = 0; jj < 8; ++jj) {
      int j = tile * TJ + ch * 8 + jj;
      float neg = 2.0f * acc[jj] - sqi - sqb[j];
      if (neg > vals[M_ - 1]) {        // strict >: earlier index wins ties
        float v = neg; int id = j;
        #pragma unroll
        for (int i = 0; i < M_; ++i) {
          if (v > vals[i]) {
            float tv = vals[i]; vals[i] = v; v = tv;
            int ti = idxs[i]; idxs[i] = id; id = ti;
          }
        }
      }
    }
    if (have) {
      float4* pw = pt4 + (cb ^ 1) * 768;
      pw[t] = st0; pw[t + 256] = st1; pw[t + 512] = st2;
      __syncthreads();
    }
  }

  // ---- pass 2: fp64 exact re-score (q from LDS) -> sorted top-16 ----
  double dsqi = sqd[b * N_ + qn];
  const double* sqdb = sqd + b * N_;
  double bd[16]; int bix[16];
  #pragma unroll
  for (int i = 0; i < 16; ++i) { bd[i] = -DBL_MAX; bix[i] = INT_MAX; }
  for (int r = 0; r < M_; ++r) {
    int j = idxs[r];
    const float4* pj = (const float4*)(base + (size_t)j * 96);
    double a0 = 0.0, a1 = 0.0, a2 = 0.0, a3 = 0.0;
    #pragma unroll
    for (int m = 0; m < 24; ++m) {
      float2 qa = sQ2[(2 * m) * 64 + ql];
      float2 qb = sQ2[(2 * m + 1) * 64 + ql];
      float4 p = pj[m];
      a0 += (double)qa.x * (double)p.x;
      a1 += (double)qa.y * (double)p.y;
      a2 += (double)qb.x * (double)p.z;
      a3 += (double)qb.y * (double)p.w;
    }
    double dneg = 2.0 * ((a0 + a1) + (a2 + a3)) - dsqi - sqdb[j];
    if (dneg > bd[15] || (dneg == bd[15] && j < bix[15])) {
      double v = dneg; int id = j;
      #pragma unroll
      for (int i = 0; i < 16; ++i) {
        if (v > bd[i] || (v == bd[i] && id < bix[i])) {
          double tv = bd[i]; bd[i] = v; v = tv;
          int ti = bix[i]; bix[i] = id; id = ti;
        }
      }
    }
  }
  __syncthreads();   // everyone done reading sQ2/pt before union reuse

  #pragma unroll
  for (int r = 0; r < 16; ++r) { mvd[ch][ql][r] = bd[r]; mi[ch][ql][r] = bix[r]; }
  mvd[ch][ql][16] = -DBL_MAX; mi[ch][ql][16] = INT_MAX;   // sentinel
  __syncthreads();

  if (t < QB) {
    int p0 = 0, p1 = 0, p2 = 0, p3 = 0;
    int* outp = knn + ((size_t)b * N_ + n0 + t) * 16;
    for (int r = 0; r < 16; ++r) {
      double v0 = mvd[0][t][p0]; int i0 = mi[0][t][p0];
      double v1 = mvd[1][t][p1]; int i1 = mi[1][t][p1];
      double v2 = mvd[2][t][p2]; int i2 = mi[2][t][p2];
      double v3 = mvd[3][t][p3]; int i3 = mi[3][t][p3];
      double bv = v0; int bi2 = i0; int bc = 0;
      if (v1 > bv || (v1 == bv && i1 < bi2)) { bv = v1; bi2 = i1; bc = 1; }
      if (v2 > bv || (v2 == bv && i2 < bi2)) { bv = v2; bi2 = i2; bc = 2; }
      if (v3 > bv || (v3 == bv && i3 < bi2)) { bv = v3; bi2 = i3; bc = 3; }
      outp[r] = bi2;
      p0 += (bc == 0); p1 += (bc == 1); p2 += (bc == 2); p3 += (bc == 3);
    }
  }
}

__device__ __forceinline__ float f4e(const float4& v, int i) {
  return i == 0 ? v.x : i == 1 ? v.y : i == 2 ? v.z : v.w;
}

// Fused main: 8 queries/block, 32 threads/query (thread = channel),
// 2 queries per wave. Weights transposed-staged in LDS as float4 [c4][o]
// (lane-contiguous b128). Neighbors read as wave-broadcast global float4
// from yT (L2/L3-resident). No cross-channel exchange thanks to E = D@W.
__global__ __launch_bounds__(256) void kC_main(
    const float* __restrict__ x, const float* __restrict__ yT,
    const int* __restrict__ knn,
    const float* __restrict__ Wq, const float* __restrict__ Eq,
    const float* __restrict__ Wk, const float* __restrict__ Ek,
    const float* __restrict__ Wv, const float* __restrict__ Ev,
    float* __restrict__ out) {
  __shared__ float4 sWq[8 * 32], sEq[8 * 32];
  __shared__ float4 sWk[16 * 32], sEk[16 * 32], sWv[16 * 32], sEv[16 * 32];
  __shared__ float sOut[8][97];

  int t = threadIdx.x;
  {
    int e = t;
    int c4 = e >> 5, o = e & 31;
    sWq[e] = ((const float4*)(Wq + o * 32))[c4];
    sEq[e] = ((const float4*)(Eq + o * 32))[c4];
  }
  for (int e = t; e < 512; e += 256) {
    int c4 = e >> 5, o = e & 31;
    sWk[e] = ((const float4*)(Wk + o * 64))[c4];
    sEk[e] = ((const float4*)(Ek + o * 64))[c4];
    sWv[e] = ((const float4*)(Wv + o * 64))[c4];
    sEv[e] = ((const float4*)(Ev + o * 64))[c4];
  }
  __syncthreads();

  int q = t >> 5, o = t & 31;
  int bno = blockIdx.x;
  int b = bno >> 9;
  int n = ((bno & 511) << 3) + q;
  int h = o >> 4, kk_mine = o & 15;

  // ---- Qx ----
  const float* xb = x + (size_t)b * 96 * N_ + n;
  float pq[3] = {0, 0, 0}, dq[3] = {0, 0, 0};
  #pragma unroll
  for (int c4 = 0; c4 < 8; ++c4) {
    float4 wq = sWq[c4 * 32 + o], eq = sEq[c4 * 32 + o];
    #pragma unroll
    for (int i = 0; i < 4; ++i) {
      int c = c4 * 4 + i;
      float w = f4e(wq, i), e2 = f4e(eq, i);
      #pragma unroll
      for (int d = 0; d < 3; ++d) {
        float xv = xb[(size_t)(c * 3 + d) * N_];
        pq[d] = fmaf(w, xv, pq[d]);
        dq[d] = fmaf(e2, xv, dq[d]);
      }
    }
  }
  float Qx[3];
  {
    float dot = pq[0] * dq[0] + pq[1] * dq[1] + pq[2] * dq[2];
    float dsq = dq[0] * dq[0] + dq[1] * dq[1] + dq[2] * dq[2] + 1e-6f;
    float r = dot / dsq;
    float qv[3];
    #pragma unroll
    for (int d = 0; d < 3; ++d) {
      float pn = pq[d] - r * dq[d];
      qv[d] = 0.2f * pq[d] + 0.8f * (dot >= 0.f ? pq[d] : pn);
    }
    float nn = sqrtf(qv[0] * qv[0] + qv[1] * qv[1] + qv[2] * qv[2]);
    float nch2 = nn * nn;
    #pragma unroll
    for (int m = 1; m <= 16; m <<= 1) nch2 += __shfl_xor(nch2, m, 32);
    float s = (nn / fmaxf(sqrtf(nch2), 1e-12f)) / fmaxf(nn, 1e-12f);
    #pragma unroll
    for (int d = 0; d < 3; ++d) Qx[d] = qv[d] * s;
  }

  const float* ctr = yT + ((size_t)b * N_ + n) * 96;
  const int* kidx = knn + ((size_t)b * N_ + n) * 16;

  // ---- K pass ----
  float pck[3] = {0, 0, 0}, dck[3] = {0, 0, 0};
  #pragma unroll
  for (int c4 = 0; c4 < 8; ++c4) {
    float4 wlo = sWk[c4 * 32 + o], whi = sWk[(c4 + 8) * 32 + o];
    float4 elo = sEk[c4 * 32 + o], ehi = sEk[(c4 + 8) * 32 + o];
    float4 c0 = ((const float4*)ctr)[c4 * 3 + 0];
    float4 c1 = ((const float4*)ctr)[c4 * 3 + 1];
    float4 c2 = ((const float4*)ctr)[c4 * 3 + 2];
    float cv[12] = {c0.x, c0.y, c0.z, c0.w, c1.x, c1.y, c1.z, c1.w, c2.x, c2.y, c2.z, c2.w};
    #pragma unroll
    for (int v = 0; v < 12; ++v) {
      int cl = v / 3, d = v % 3;
      pck[d] = fmaf(f4e(whi, cl) - f4e(wlo, cl), cv[v], pck[d]);
      dck[d] = fmaf(f4e(ehi, cl) - f4e(elo, cl), cv[v], dck[d]);
    }
  }

  float myscore = 0.f;
  #pragma unroll 1
  for (int k = 0; k < 16; ++k) {
    int jn = kidx[k];
    const float* nb = yT + ((size_t)b * N_ + jn) * 96;
    float p[3] = {pck[0], pck[1], pck[2]}, dd[3] = {dck[0], dck[1], dck[2]};
    #pragma unroll
    for (int c4 = 0; c4 < 8; ++c4) {
      float4 w = sWk[c4 * 32 + o], e = sEk[c4 * 32 + o];
      float4 n0 = ((const float4*)nb)[c4 * 3 + 0];
      float4 n1 = ((const float4*)nb)[c4 * 3 + 1];
      float4 n2 = ((const float4*)nb)[c4 * 3 + 2];
      float nv[12] = {n0.x, n0.y, n0.z, n0.w, n1.x, n1.y, n1.z, n1.w, n2.x, n2.y, n2.z, n2.w};
      #pragma unroll
      for (int v = 0; v < 12; ++v) {
        int cl = v / 3, d = v % 3;
        p[d]  = fmaf(f4e(w, cl), nv[v], p[d]);
        dd[d] = fmaf(f4e(e, cl), nv[v], dd[d]);
      }
    }
    float dot = p[0] * dd[0] + p[1] * dd[1] + p[2] * dd[2];
    float dsq = dd[0] * dd[0] + dd[1] * dd[1] + dd[2] * dd[2] + 1e-6f;
    float r = dot / dsq;
    float ky[3];
    #pragma unroll
    for (int d = 0; d < 3; ++d) {
      float pn = p[d] - r * dd[d];
      ky[d] = 0.2f * p[d] + 0.8f * (dot >= 0.f ? p[d] : pn);
    }
    float nn = sqrtf(ky[0] * ky[0] + ky[1] * ky[1] + ky[2] * ky[2]);
    float nch2 = nn * nn;
    #pragma unroll
    for (int m = 1; m <= 16; m <<= 1) nch2 += __shfl_xor(nch2, m, 32);
    float s = (1.f / fmaxf(sqrtf(nch2), 1e-12f)) * (nn / fmaxf(nn, 1e-12f));
    float qk = (ky[0] * Qx[0] + ky[1] * Qx[1] + ky[2] * Qx[2]) * s;
    #pragma unroll
    for (int m = 1; m <= 8; m <<= 1) qk += __shfl_xor(qk, m, 32);
    float score = qk * 0.14433756729740643f;   // 1/sqrt(48)
    if (kk_mine == k) myscore = score;
  }

  // ---- softmax ----
  float att_mine;
  {
    float mx = myscore;
    #pragma unroll
    for (int m = 1; m <= 8; m <<= 1) mx = fmaxf(mx, __shfl_xor(mx, m, 32));
    float ex = expf(myscore - mx);
    float ss = ex;
    #pragma unroll
    for (int m = 1; m <= 8; m <<= 1) ss += __shfl_xor(ss, m, 32);
    att_mine = ex / ss;
  }

  // ---- V pass ----
  float pcv[3] = {0, 0, 0}, dcv[3] = {0, 0, 0};
  #pragma unroll
  for (int c4 = 0; c4 < 8; ++c4) {
    float4 wlo = sWv[c4 * 32 + o], whi = sWv[(c4 + 8) * 32 + o];
    float4 elo = sEv[c4 * 32 + o], ehi = sEv[(c4 + 8) * 32 + o];
    float4 c0 = ((const float4*)ctr)[c4 * 3 + 0];
    float4 c1 = ((const float4*)ctr)[c4 * 3 + 1];
    float4 c2 = ((const float4*)ctr)[c4 * 3 + 2];
    float cv[12] = {c0.x, c0.y, c0.z, c0.w, c1.x, c1.y, c1.z, c1.w, c2.x, c2.y, c2.z, c2.w};
    #pragma unroll
    for (int v = 0; v < 12; ++v) {
      int cl = v / 3, d = v % 3;
      pcv[d] = fmaf(f4e(whi, cl) - f4e(wlo, cl), cv[v], pcv[d]);
      dcv[d] = fmaf(f4e(ehi, cl) - f4e(elo, cl), cv[v], dcv[d]);
    }
  }
  float acc[3] = {0, 0, 0};
  #pragma unroll 1
  for (int k = 0; k < 16; ++k) {
    int jn = kidx[k];
    const float* nb = yT + ((size_t)b * N_ + jn) * 96;
    float p[3] = {pcv[0], pcv[1], pcv[2]}, dd[3] = {dcv[0], dcv[1], dcv[2]};
    #pragma unroll
    for (int c4 = 0; c4 < 8; ++c4) {
      float4 w = sWv[c4 * 32 + o], e = sEv[c4 * 32 + o];
      float4 n0 = ((const float4*)nb)[c4 * 3 + 0];
      float4 n1 = ((const float4*)nb)[c4 * 3 + 1];
      float4 n2 = ((const float4*)nb)[c4 * 3 + 2];
      float nv[12] = {n0.x, n0.y, n0.z, n0.w, n1.x, n1.y, n1.z, n1.w, n2.x, n2.y, n2.z, n2.w};
      #pragma unroll
      for (int v = 0; v < 12; ++v) {
        int cl = v / 3, d = v % 3;
        p[d]  = fmaf(f4e(w, cl), nv[v], p[d]);
        dd[d] = fmaf(f4e(e, cl), nv[v], dd[d]);
      }
    }
    float dot = p[0] * dd[0] + p[1] * dd[1] + p[2] * dd[2];
    float dsq = dd[0] * dd[0] + dd[1] * dd[1] + dd[2] * dd[2] + 1e-6f;
    float r = dot / dsq;
    float attk = __shfl(att_mine, h * 16 + k, 32);
    #pragma unroll
    for (int d = 0; d < 3; ++d) {
      float pn = p[d] - r * dd[d];
      float vy = 0.2f * p[d] + 0.8f * (dot >= 0.f ? p[d] : pn);
      acc[d] = fmaf(attk, vy, acc[d]);
    }
  }

  // ---- output ----
  #pragma unroll
  for (int d = 0; d < 3; ++d) sOut[q][o * 3 + d] = acc[d];
  __syncthreads();
  int nl = t & 7;
  int n_out = ((bno & 511) << 3) + nl;
  #pragma unroll
  for (int it = 0; it < 3; ++it) {
    int od = it * 32 + (t >> 3);
    size_t a = (size_t)b * 96 * N_ + (size_t)od * N_ + n_out;
    out[a] = x[a] + sOut[nl][od];
  }
}

extern "C" void kernel_launch(void* const* d_in, const int* in_sizes, int n_in,
                              void* d_out, int out_size, void* d_ws, size_t ws_size,
                              hipStream_t stream) {
  const float* x  = (const float*)d_in[0];
  const float* y  = (const float*)d_in[1];
  const float* Wq = (const float*)d_in[2];
  const float* Dq = (const float*)d_in[3];
  const float* Wk = (const float*)d_in[4];
  const float* Dk = (const float*)d_in[5];
  const float* Wv = (const float*)d_in[6];
  const float* Dv = (const float*)d_in[7];
  float* out = (float*)d_out;

  float*  ws  = (float*)d_ws;
  float*  yT  = ws;                                     // [B][N][96]
  float*  sq  = yT + (size_t)B_ * N_ * 96;              // [B][N]
  int*    knn = (int*)(sq + B_ * N_);                   // [B][N][16]
  double* sqd = (double*)(knn + (size_t)B_ * N_ * 16);  // [B][N]
  float*  Ek  = (float*)(sqd + (size_t)B_ * N_);        // [32][64]
  float*  Ev  = Ek + 2048;                              // [32][64]
  float*  Eq  = Ev + 2048;                              // [32][32]

  kE_combine<<<dim3(1), dim3(256), 0, stream>>>(Wk, Dk, Wv, Dv, Wq, Dq, Ek, Ev, Eq);
  kA_transpose<<<dim3(512), dim3(256), 0, stream>>>(y, yT, sq, sqd);
  kB_knn<<<dim3(512), dim3(256), 0, stream>>>(yT, sq, sqd, knn);
  kC_main<<<dim3(4096), dim3(256), 0, stream>>>(x, yT, knn, Wq, Eq, Wk, Ek, Wv, Ev, out);
}

// Round 5
// 6938.234 us; speedup vs baseline: 2.4474x; 2.4474x over previous
//
#include <hip/hip_runtime.h>
#include <math.h>
#include <float.h>
#include <limits.h>

#define B_ 8
#define C_ 32
#define N_ 4096
#define K_ 16
#define M_ 20   // per-chunk fp32 candidate margin (>=16)
#define QB 32   // queries per kB block
#define TJ 32   // neighbor tile points

// ------------------------------------------------------------------
// ws layout:
//   yT  : [B][N][96] float   3,145,728 f
//   sq  : [B][N]     float      32,768 f
//   knn : [B][N][16] int       524,288 i
//   sqd : [B][N]     double     32,768 d  (8B-aligned)
//   Ek  : [32][64]   float       2,048 f
//   Ev  : [32][64]   float       2,048 f
//   Eq  : [32][32]   float       1,024 f
// ------------------------------------------------------------------

__global__ __launch_bounds__(256) void kE_combine(
    const float* __restrict__ Wk, const float* __restrict__ Dk,
    const float* __restrict__ Wv, const float* __restrict__ Dv,
    const float* __restrict__ Wq, const float* __restrict__ Dq,
    float* __restrict__ Ek, float* __restrict__ Ev, float* __restrict__ Eq) {
  int t = threadIdx.x;
  for (int e = t; e < 2048; e += 256) {
    int o = e >> 6, c = e & 63;
    float a = 0.f, v = 0.f;
    for (int m = 0; m < 32; ++m) {
      a = fmaf(Dk[o * 32 + m], Wk[m * 64 + c], a);
      v = fmaf(Dv[o * 32 + m], Wv[m * 64 + c], v);
    }
    Ek[e] = a; Ev[e] = v;
  }
  for (int e = t; e < 1024; e += 256) {
    int o = e >> 5, c = e & 31;
    float a = 0.f;
    for (int m = 0; m < 32; ++m) a = fmaf(Dq[o * 32 + m], Wq[m * 32 + c], a);
    Eq[e] = a;
  }
}

// transpose y [B][96][N] -> yT [B][N][96]; sq (fp32) and sqd (fp64)
__global__ __launch_bounds__(256) void kA_transpose(
    const float* __restrict__ y, float* __restrict__ yT,
    float* __restrict__ sq, double* __restrict__ sqd) {
  __shared__ float tile[96][65];
  int b = blockIdx.x >> 6;
  int n0 = (blockIdx.x & 63) * 64;
  int t = threadIdx.x;
  int g = t >> 6, ln = t & 63;
  #pragma unroll
  for (int r = 0; r < 24; ++r) {
    int d = g * 24 + r;
    tile[d][ln] = y[((size_t)b * 96 + d) * N_ + n0 + ln];
  }
  __syncthreads();
  if (t < 64) {
    float s = 0.f; double sd = 0.0;
    #pragma unroll
    for (int d = 0; d < 96; ++d) {
      float v = tile[d][t];
      s = fmaf(v, v, s);
      sd += (double)v * (double)v;
    }
    sq[b * N_ + n0 + t] = s;
    sqd[b * N_ + n0 + t] = sd;
  }
  for (int idx = t; idx < 64 * 96; idx += 256) {
    int nl = idx / 96, d = idx % 96;
    yT[((size_t)b * N_ + n0 + nl) * 96 + d] = tile[d][nl];
  }
}

// kNN, LDS-tiled scan. Block = 256 threads = 32 queries x 8 chunks.
// q4[24] in registers (96 VGPR, uncapped allocator -> no spills).
// Neighbor tiles (32 pts) double-buffered in LDS, read as 2-way
// broadcast b128 (free). j-outer loop with unroll 1 bounds scheduler
// hoisting to one j's loads. sqj loaded early per j (latency hidden
// under the 96-FMA chain).
// Pass 1: fp32 per-thread top-20. Pass 2: fp64 exact re-score -> sorted
// top-16. Merge: 32 threads do exact 8-way merge (scalar pointers).
__global__ __launch_bounds__(256) void kB_knn(
    const float* __restrict__ yT, const float* __restrict__ sq,
    const double* __restrict__ sqd, int* __restrict__ knn) {
  // union: scan tiles pt [2][768] f4 (24,576 B)
  //        merge: mvd [8][32][17] dbl (34,816 B) + mi [8][32][17] int (17,408 B)
  __shared__ __align__(16) char smem[52224];
  float4* pt = (float4*)smem;                        // [2][768]
  double (*mvd)[QB][17] = (double(*)[QB][17])smem;   // [8][32][17]
  int    (*mi)[QB][17]  = (int(*)[QB][17])(smem + 8 * QB * 17 * 8);

  int t = threadIdx.x;
  int ql = t & 31, ch = t >> 5;
  int b = blockIdx.x >> 7;            // 128 blocks per batch
  int n0 = (blockIdx.x & 127) * QB;
  int qn = n0 + ql;

  const float* base = yT + (size_t)b * N_ * 96;
  const float* qp = base + (size_t)qn * 96;
  float4 q4[24];
  #pragma unroll
  for (int m = 0; m < 24; ++m) q4[m] = ((const float4*)qp)[m];
  float sqi = sq[b * N_ + qn];
  const float* sqb = sq + b * N_;

  float vals[M_]; int idxs[M_];
  #pragma unroll
  for (int i = 0; i < M_; ++i) { vals[i] = -FLT_MAX; idxs[i] = 0; }

  // prologue: stage tile 0
  {
    const float4* g = (const float4*)base;
    pt[t] = g[t]; pt[t + 256] = g[t + 256]; pt[t + 512] = g[t + 512];
  }
  __syncthreads();

  for (int tile = 0; tile < 128; ++tile) {
    int cb = tile & 1;
    float4 st0, st1, st2;
    bool have = (tile + 1) < 128;
    if (have) {
      const float4* g = (const float4*)(base + (size_t)(tile + 1) * TJ * 96);
      st0 = g[t]; st1 = g[t + 256]; st2 = g[t + 512];
    }
    #pragma unroll 1
    for (int jj = 0; jj < 4; ++jj) {
      int jloc = ch * 4 + jj;
      int j = tile * TJ + jloc;
      float sqj = sqb[j];                       // early issue, late use
      const float4* pr = pt + cb * 768 + jloc * 24;
      float a0 = 0.f, a1 = 0.f, a2 = 0.f, a3 = 0.f;
      #pragma unroll
      for (int m = 0; m < 24; ++m) {
        float4 p = pr[m];
        a0 = fmaf(q4[m].x, p.x, a0);
        a1 = fmaf(q4[m].y, p.y, a1);
        a2 = fmaf(q4[m].z, p.z, a2);
        a3 = fmaf(q4[m].w, p.w, a3);
      }
      float neg = 2.0f * ((a0 + a1) + (a2 + a3)) - sqi - sqj;
      if (neg > vals[M_ - 1]) {        // strict >: earlier index wins ties
        float v = neg; int id = j;
        #pragma unroll
        for (int i = 0; i < M_; ++i) {
          if (v > vals[i]) {
            float tv = vals[i]; vals[i] = v; v = tv;
            int ti = idxs[i]; idxs[i] = id; id = ti;
          }
        }
      }
    }
    if (have) {
      float4* pw = pt + (cb ^ 1) * 768;
      pw[t] = st0; pw[t + 256] = st1; pw[t + 512] = st2;
    }
    __syncthreads();
  }

  // ---- pass 2: fp64 exact re-score of the 20 -> sorted top-16 ----
  double dsqi = sqd[b * N_ + qn];
  const double* sqdb = sqd + b * N_;
  double bd[16]; int bix[16];
  #pragma unroll
  for (int i = 0; i < 16; ++i) { bd[i] = -DBL_MAX; bix[i] = INT_MAX; }
  #pragma unroll 1
  for (int r = 0; r < M_; ++r) {
    int j = idxs[r];
    const float4* pj = (const float4*)(base + (size_t)j * 96);
    double a0 = 0.0, a1 = 0.0, a2 = 0.0, a3 = 0.0;
    #pragma unroll
    for (int m = 0; m < 24; ++m) {
      float4 p = pj[m];
      a0 += (double)q4[m].x * (double)p.x;
      a1 += (double)q4[m].y * (double)p.y;
      a2 += (double)q4[m].z * (double)p.z;
      a3 += (double)q4[m].w * (double)p.w;
    }
    double dneg = 2.0 * ((a0 + a1) + (a2 + a3)) - dsqi - sqdb[j];
    if (dneg > bd[15] || (dneg == bd[15] && j < bix[15])) {
      double v = dneg; int id = j;
      #pragma unroll
      for (int i = 0; i < 16; ++i) {
        if (v > bd[i] || (v == bd[i] && id < bix[i])) {
          double tv = bd[i]; bd[i] = v; v = tv;
          int ti = bix[i]; bix[i] = id; id = ti;
        }
      }
    }
  }
  __syncthreads();   // all tile reads done before union reuse (covered by loop barrier too)

  #pragma unroll
  for (int r = 0; r < 16; ++r) { mvd[ch][ql][r] = bd[r]; mi[ch][ql][r] = bix[r]; }
  mvd[ch][ql][16] = -DBL_MAX; mi[ch][ql][16] = INT_MAX;   // sentinel
  __syncthreads();

  if (t < QB) {
    int p0 = 0, p1 = 0, p2 = 0, p3 = 0, p4 = 0, p5 = 0, p6 = 0, p7 = 0;
    int* outp = knn + ((size_t)b * N_ + n0 + t) * 16;
    for (int r = 0; r < 16; ++r) {
      double bv = mvd[0][t][p0]; int bi2 = mi[0][t][p0]; int bc = 0;
      { double v = mvd[1][t][p1]; int id = mi[1][t][p1];
        if (v > bv || (v == bv && id < bi2)) { bv = v; bi2 = id; bc = 1; } }
      { double v = mvd[2][t][p2]; int id = mi[2][t][p2];
        if (v > bv || (v == bv && id < bi2)) { bv = v; bi2 = id; bc = 2; } }
      { double v = mvd[3][t][p3]; int id = mi[3][t][p3];
        if (v > bv || (v == bv && id < bi2)) { bv = v; bi2 = id; bc = 3; } }
      { double v = mvd[4][t][p4]; int id = mi[4][t][p4];
        if (v > bv || (v == bv && id < bi2)) { bv = v; bi2 = id; bc = 4; } }
      { double v = mvd[5][t][p5]; int id = mi[5][t][p5];
        if (v > bv || (v == bv && id < bi2)) { bv = v; bi2 = id; bc = 5; } }
      { double v = mvd[6][t][p6]; int id = mi[6][t][p6];
        if (v > bv || (v == bv && id < bi2)) { bv = v; bi2 = id; bc = 6; } }
      { double v = mvd[7][t][p7]; int id = mi[7][t][p7];
        if (v > bv || (v == bv && id < bi2)) { bv = v; bi2 = id; bc = 7; } }
      outp[r] = bi2;
      p0 += (bc == 0); p1 += (bc == 1); p2 += (bc == 2); p3 += (bc == 3);
      p4 += (bc == 4); p5 += (bc == 5); p6 += (bc == 6); p7 += (bc == 7);
    }
  }
}

__device__ __forceinline__ float f4e(const float4& v, int i) {
  return i == 0 ? v.x : i == 1 ? v.y : i == 2 ? v.z : v.w;
}

// Fused main: 8 queries/block, 32 threads/query (thread = channel),
// 2 queries per wave. Weights transposed-staged in LDS as float4 [c4][o]
// (lane-contiguous b128). Neighbors read as wave-broadcast global float4
// from yT (L2/L3-resident). No cross-channel exchange thanks to E = D@W.
__global__ __launch_bounds__(256) void kC_main(
    const float* __restrict__ x, const float* __restrict__ yT,
    const int* __restrict__ knn,
    const float* __restrict__ Wq, const float* __restrict__ Eq,
    const float* __restrict__ Wk, const float* __restrict__ Ek,
    const float* __restrict__ Wv, const float* __restrict__ Ev,
    float* __restrict__ out) {
  __shared__ float4 sWq[8 * 32], sEq[8 * 32];
  __shared__ float4 sWk[16 * 32], sEk[16 * 32], sWv[16 * 32], sEv[16 * 32];
  __shared__ float sOut[8][97];

  int t = threadIdx.x;
  {
    int e = t;
    int c4 = e >> 5, o = e & 31;
    sWq[e] = ((const float4*)(Wq + o * 32))[c4];
    sEq[e] = ((const float4*)(Eq + o * 32))[c4];
  }
  for (int e = t; e < 512; e += 256) {
    int c4 = e >> 5, o = e & 31;
    sWk[e] = ((const float4*)(Wk + o * 64))[c4];
    sEk[e] = ((const float4*)(Ek + o * 64))[c4];
    sWv[e] = ((const float4*)(Wv + o * 64))[c4];
    sEv[e] = ((const float4*)(Ev + o * 64))[c4];
  }
  __syncthreads();

  int q = t >> 5, o = t & 31;
  int bno = blockIdx.x;
  int b = bno >> 9;
  int n = ((bno & 511) << 3) + q;
  int h = o >> 4, kk_mine = o & 15;

  // ---- Qx ----
  const float* xb = x + (size_t)b * 96 * N_ + n;
  float pq[3] = {0, 0, 0}, dq[3] = {0, 0, 0};
  #pragma unroll
  for (int c4 = 0; c4 < 8; ++c4) {
    float4 wq = sWq[c4 * 32 + o], eq = sEq[c4 * 32 + o];
    #pragma unroll
    for (int i = 0; i < 4; ++i) {
      int c = c4 * 4 + i;
      float w = f4e(wq, i), e2 = f4e(eq, i);
      #pragma unroll
      for (int d = 0; d < 3; ++d) {
        float xv = xb[(size_t)(c * 3 + d) * N_];
        pq[d] = fmaf(w, xv, pq[d]);
        dq[d] = fmaf(e2, xv, dq[d]);
      }
    }
  }
  float Qx[3];
  {
    float dot = pq[0] * dq[0] + pq[1] * dq[1] + pq[2] * dq[2];
    float dsq = dq[0] * dq[0] + dq[1] * dq[1] + dq[2] * dq[2] + 1e-6f;
    float r = dot / dsq;
    float qv[3];
    #pragma unroll
    for (int d = 0; d < 3; ++d) {
      float pn = pq[d] - r * dq[d];
      qv[d] = 0.2f * pq[d] + 0.8f * (dot >= 0.f ? pq[d] : pn);
    }
    float nn = sqrtf(qv[0] * qv[0] + qv[1] * qv[1] + qv[2] * qv[2]);
    float nch2 = nn * nn;
    #pragma unroll
    for (int m = 1; m <= 16; m <<= 1) nch2 += __shfl_xor(nch2, m, 32);
    float s = (nn / fmaxf(sqrtf(nch2), 1e-12f)) / fmaxf(nn, 1e-12f);
    #pragma unroll
    for (int d = 0; d < 3; ++d) Qx[d] = qv[d] * s;
  }

  const float* ctr = yT + ((size_t)b * N_ + n) * 96;
  const int* kidx = knn + ((size_t)b * N_ + n) * 16;

  // ---- K pass ----
  float pck[3] = {0, 0, 0}, dck[3] = {0, 0, 0};
  #pragma unroll
  for (int c4 = 0; c4 < 8; ++c4) {
    float4 wlo = sWk[c4 * 32 + o], whi = sWk[(c4 + 8) * 32 + o];
    float4 elo = sEk[c4 * 32 + o], ehi = sEk[(c4 + 8) * 32 + o];
    float4 c0 = ((const float4*)ctr)[c4 * 3 + 0];
    float4 c1 = ((const float4*)ctr)[c4 * 3 + 1];
    float4 c2 = ((const float4*)ctr)[c4 * 3 + 2];
    float cv[12] = {c0.x, c0.y, c0.z, c0.w, c1.x, c1.y, c1.z, c1.w, c2.x, c2.y, c2.z, c2.w};
    #pragma unroll
    for (int v = 0; v < 12; ++v) {
      int cl = v / 3, d = v % 3;
      pck[d] = fmaf(f4e(whi, cl) - f4e(wlo, cl), cv[v], pck[d]);
      dck[d] = fmaf(f4e(ehi, cl) - f4e(elo, cl), cv[v], dck[d]);
    }
  }

  float myscore = 0.f;
  #pragma unroll 1
  for (int k = 0; k < 16; ++k) {
    int jn = kidx[k];
    const float* nb = yT + ((size_t)b * N_ + jn) * 96;
    float p[3] = {pck[0], pck[1], pck[2]}, dd[3] = {dck[0], dck[1], dck[2]};
    #pragma unroll
    for (int c4 = 0; c4 < 8; ++c4) {
      float4 w = sWk[c4 * 32 + o], e = sEk[c4 * 32 + o];
      float4 n0 = ((const float4*)nb)[c4 * 3 + 0];
      float4 n1 = ((const float4*)nb)[c4 * 3 + 1];
      float4 n2 = ((const float4*)nb)[c4 * 3 + 2];
      float nv[12] = {n0.x, n0.y, n0.z, n0.w, n1.x, n1.y, n1.z, n1.w, n2.x, n2.y, n2.z, n2.w};
      #pragma unroll
      for (int v = 0; v < 12; ++v) {
        int cl = v / 3, d = v % 3;
        p[d]  = fmaf(f4e(w, cl), nv[v], p[d]);
        dd[d] = fmaf(f4e(e, cl), nv[v], dd[d]);
      }
    }
    float dot = p[0] * dd[0] + p[1] * dd[1] + p[2] * dd[2];
    float dsq = dd[0] * dd[0] + dd[1] * dd[1] + dd[2] * dd[2] + 1e-6f;
    float r = dot / dsq;
    float ky[3];
    #pragma unroll
    for (int d = 0; d < 3; ++d) {
      float pn = p[d] - r * dd[d];
      ky[d] = 0.2f * p[d] + 0.8f * (dot >= 0.f ? p[d] : pn);
    }
    float nn = sqrtf(ky[0] * ky[0] + ky[1] * ky[1] + ky[2] * ky[2]);
    float nch2 = nn * nn;
    #pragma unroll
    for (int m = 1; m <= 16; m <<= 1) nch2 += __shfl_xor(nch2, m, 32);
    float s = (1.f / fmaxf(sqrtf(nch2), 1e-12f)) * (nn / fmaxf(nn, 1e-12f));
    float qk = (ky[0] * Qx[0] + ky[1] * Qx[1] + ky[2] * Qx[2]) * s;
    #pragma unroll
    for (int m = 1; m <= 8; m <<= 1) qk += __shfl_xor(qk, m, 32);
    float score = qk * 0.14433756729740643f;   // 1/sqrt(48)
    if (kk_mine == k) myscore = score;
  }

  // ---- softmax ----
  float att_mine;
  {
    float mx = myscore;
    #pragma unroll
    for (int m = 1; m <= 8; m <<= 1) mx = fmaxf(mx, __shfl_xor(mx, m, 32));
    float ex = expf(myscore - mx);
    float ss = ex;
    #pragma unroll
    for (int m = 1; m <= 8; m <<= 1) ss += __shfl_xor(ss, m, 32);
    att_mine = ex / ss;
  }

  // ---- V pass ----
  float pcv[3] = {0, 0, 0}, dcv[3] = {0, 0, 0};
  #pragma unroll
  for (int c4 = 0; c4 < 8; ++c4) {
    float4 wlo = sWv[c4 * 32 + o], whi = sWv[(c4 + 8) * 32 + o];
    float4 elo = sEv[c4 * 32 + o], ehi = sEv[(c4 + 8) * 32 + o];
    float4 c0 = ((const float4*)ctr)[c4 * 3 + 0];
    float4 c1 = ((const float4*)ctr)[c4 * 3 + 1];
    float4 c2 = ((const float4*)ctr)[c4 * 3 + 2];
    float cv[12] = {c0.x, c0.y, c0.z, c0.w, c1.x, c1.y, c1.z, c1.w, c2.x, c2.y, c2.z, c2.w};
    #pragma unroll
    for (int v = 0; v < 12; ++v) {
      int cl = v / 3, d = v % 3;
      pcv[d] = fmaf(f4e(whi, cl) - f4e(wlo, cl), cv[v], pcv[d]);
      dcv[d] = fmaf(f4e(ehi, cl) - f4e(elo, cl), cv[v], dcv[d]);
    }
  }
  float acc[3] = {0, 0, 0};
  #pragma unroll 1
  for (int k = 0; k < 16; ++k) {
    int jn = kidx[k];
    const float* nb = yT + ((size_t)b * N_ + jn) * 96;
    float p[3] = {pcv[0], pcv[1], pcv[2]}, dd[3] = {dcv[0], dcv[1], dcv[2]};
    #pragma unroll
    for (int c4 = 0; c4 < 8; ++c4) {
      float4 w = sWv[c4 * 32 + o], e = sEv[c4 * 32 + o];
      float4 n0 = ((const float4*)nb)[c4 * 3 + 0];
      float4 n1 = ((const float4*)nb)[c4 * 3 + 1];
      float4 n2 = ((const float4*)nb)[c4 * 3 + 2];
      float nv[12] = {n0.x, n0.y, n0.z, n0.w, n1.x, n1.y, n1.z, n1.w, n2.x, n2.y, n2.z, n2.w};
      #pragma unroll
      for (int v = 0; v < 12; ++v) {
        int cl = v / 3, d = v % 3;
        p[d]  = fmaf(f4e(w, cl), nv[v], p[d]);
        dd[d] = fmaf(f4e(e, cl), nv[v], dd[d]);
      }
    }
    float dot = p[0] * dd[0] + p[1] * dd[1] + p[2] * dd[2];
    float dsq = dd[0] * dd[0] + dd[1] * dd[1] + dd[2] * dd[2] + 1e-6f;
    float r = dot / dsq;
    float attk = __shfl(att_mine, h * 16 + k, 32);
    #pragma unroll
    for (int d = 0; d < 3; ++d) {
      float pn = p[d] - r * dd[d];
      float vy = 0.2f * p[d] + 0.8f * (dot >= 0.f ? p[d] : pn);
      acc[d] = fmaf(attk, vy, acc[d]);
    }
  }

  // ---- output ----
  #pragma unroll
  for (int d = 0; d < 3; ++d) sOut[q][o * 3 + d] = acc[d];
  __syncthreads();
  int nl = t & 7;
  int n_out = ((bno & 511) << 3) + nl;
  #pragma unroll
  for (int it = 0; it < 3; ++it) {
    int od = it * 32 + (t >> 3);
    size_t a = (size_t)b * 96 * N_ + (size_t)od * N_ + n_out;
    out[a] = x[a] + sOut[nl][od];
  }
}

extern "C" void kernel_launch(void* const* d_in, const int* in_sizes, int n_in,
                              void* d_out, int out_size, void* d_ws, size_t ws_size,
                              hipStream_t stream) {
  const float* x  = (const float*)d_in[0];
  const float* y  = (const float*)d_in[1];
  const float* Wq = (const float*)d_in[2];
  const float* Dq = (const float*)d_in[3];
  const float* Wk = (const float*)d_in[4];
  const float* Dk = (const float*)d_in[5];
  const float* Wv = (const float*)d_in[6];
  const float* Dv = (const float*)d_in[7];
  float* out = (float*)d_out;

  float*  ws  = (float*)d_ws;
  float*  yT  = ws;                                     // [B][N][96]
  float*  sq  = yT + (size_t)B_ * N_ * 96;              // [B][N]
  int*    knn = (int*)(sq + B_ * N_);                   // [B][N][16]
  double* sqd = (double*)(knn + (size_t)B_ * N_ * 16);  // [B][N]
  float*  Ek  = (float*)(sqd + (size_t)B_ * N_);        // [32][64]
  float*  Ev  = Ek + 2048;                              // [32][64]
  float*  Eq  = Ev + 2048;                              // [32][32]

  kE_combine<<<dim3(1), dim3(256), 0, stream>>>(Wk, Dk, Wv, Dv, Wq, Dq, Ek, Ev, Eq);
  kA_transpose<<<dim3(512), dim3(256), 0, stream>>>(y, yT, sq, sqd);
  kB_knn<<<dim3(1024), dim3(256), 0, stream>>>(yT, sq, sqd, knn);
  kC_main<<<dim3(4096), dim3(256), 0, stream>>>(x, yT, knn, Wq, Eq, Wk, Ek, Wv, Ev, out);
}

// Round 6
// 2032.946 us; speedup vs baseline: 8.3526x; 3.4129x over previous
//
#include <hip/hip_runtime.h>
#include <math.h>
#include <float.h>
#include <limits.h>

#define B_ 8
#define C_ 32
#define N_ 4096
#define K_ 16
#define M_ 16   // per-chunk candidate count (fp64 re-scored)

typedef __attribute__((ext_vector_type(8))) short bf16x8;
typedef __attribute__((ext_vector_type(4))) float f32x4;
#define MFMA16(a, b, c) __builtin_amdgcn_mfma_f32_16x16x32_bf16(a, b, c, 0, 0, 0)

// ------------------------------------------------------------------
// ws layout (bytes):
//   yT  : [B][N][96] float    12,582,912
//   sqd : [B][N]     double      262,144   (8B aligned)
//   sq  : [B][N]     float       131,072
//   knn : [B][N][16] int       2,097,152
//   hB  : [B][N][96] ushort    6,291,456   (bf16 hi)
//   lB  : [B][N][96] ushort    6,291,456   (bf16 lo)
//   Ek/Ev/Eq floats               20,480
// total ~27.7 MB
// ------------------------------------------------------------------

__global__ __launch_bounds__(256) void kE_combine(
    const float* __restrict__ Wk, const float* __restrict__ Dk,
    const float* __restrict__ Wv, const float* __restrict__ Dv,
    const float* __restrict__ Wq, const float* __restrict__ Dq,
    float* __restrict__ Ek, float* __restrict__ Ev, float* __restrict__ Eq) {
  int t = threadIdx.x;
  for (int e = t; e < 2048; e += 256) {
    int o = e >> 6, c = e & 63;
    float a = 0.f, v = 0.f;
    for (int m = 0; m < 32; ++m) {
      a = fmaf(Dk[o * 32 + m], Wk[m * 64 + c], a);
      v = fmaf(Dv[o * 32 + m], Wv[m * 64 + c], v);
    }
    Ek[e] = a; Ev[e] = v;
  }
  for (int e = t; e < 1024; e += 256) {
    int o = e >> 5, c = e & 31;
    float a = 0.f;
    for (int m = 0; m < 32; ++m) a = fmaf(Dq[o * 32 + m], Wq[m * 32 + c], a);
    Eq[e] = a;
  }
}

// transpose y [B][96][N] -> yT [B][N][96]; sq fp32; sqd fp64;
// hB/lB = bf16 hi/lo split of yT (h = trunc16(x), l = trunc16(x - h)).
__global__ __launch_bounds__(256) void kA_transpose(
    const float* __restrict__ y, float* __restrict__ yT,
    float* __restrict__ sq, double* __restrict__ sqd,
    ushort* __restrict__ hB, ushort* __restrict__ lB) {
  __shared__ float tile[96][65];
  int b = blockIdx.x >> 6;
  int n0 = (blockIdx.x & 63) * 64;
  int t = threadIdx.x;
  int g = t >> 6, ln = t & 63;
  #pragma unroll
  for (int r = 0; r < 24; ++r) {
    int d = g * 24 + r;
    tile[d][ln] = y[((size_t)b * 96 + d) * N_ + n0 + ln];
  }
  __syncthreads();
  if (t < 64) {
    float s = 0.f; double sd = 0.0;
    #pragma unroll
    for (int d = 0; d < 96; ++d) {
      float v = tile[d][t];
      s = fmaf(v, v, s);
      sd += (double)v * (double)v;
    }
    sq[b * N_ + n0 + t] = s;
    sqd[b * N_ + n0 + t] = sd;
  }
  for (int idx = t; idx < 64 * 96; idx += 256) {
    int nl = idx / 96, d = idx % 96;
    float v = tile[d][nl];
    size_t o = ((size_t)b * N_ + n0 + nl) * 96 + d;
    yT[o] = v;
    unsigned xb = __float_as_uint(v);
    ushort h = (ushort)(xb >> 16);
    float hf = __uint_as_float((unsigned)h << 16);
    float r2 = v - hf;                       // exact
    ushort l = (ushort)(__float_as_uint(r2) >> 16);
    hB[o] = h; lB[o] = l;
  }
}

// kNN via bf16-split MFMA GEMM (K=288: h.h + l.h + h.l), fused top-16
// selection, fp64 exact re-score, 4-way exact merge.
// Block = 256 thr = 4 waves; wave w owns 16-query stripe; j-tiles of 64.
__global__ __launch_bounds__(256) void kB_knn(
    const float* __restrict__ yT, const ushort* __restrict__ hB,
    const ushort* __restrict__ lB, const float* __restrict__ sq,
    const double* __restrict__ sqd, int* __restrict__ knn) {
  // union: sS [2][64][65] f32 (33,280 B)  |  mvd [4][64][17] dbl (34,816)
  //                                          + mi [4][64][17] int (17,408)
  __shared__ __align__(16) char smem[52224];
  float (*sS)[64][65] = (float (*)[64][65])smem;
  double (*mvd)[64][17] = (double (*)[64][17])smem;
  int    (*mi)[64][17]  = (int (*)[64][17])(smem + 34816);

  const int t = threadIdx.x;
  const int lane = t & 63;
  const int w = t >> 6;
  const int b = blockIdx.x >> 6;            // 64 blocks per batch
  const int n0 = (blockIdx.x & 63) * 64;
  const int bN = b * N_;

  const ushort* hb = hB + (size_t)bN * 96;
  const size_t ldelta = (size_t)(lB - hB);  // element offset hb -> lb
  const float* sqb = sq + bN;

  const int fm = lane & 15;                 // frag row (A) / col (B)
  const int fg = lane >> 4;                 // k-octet group

  // A-frags: wave's 16 queries (rows n0 + w*16 + fm), resident in regs.
  const ushort* arow = hb + (size_t)(n0 + w * 16 + fm) * 96 + fg * 8;
  const bf16x8 ah0 = *(const bf16x8*)(arow);
  const bf16x8 ah1 = *(const bf16x8*)(arow + 32);
  const bf16x8 ah2 = *(const bf16x8*)(arow + 64);
  const bf16x8 al0 = *(const bf16x8*)(arow + ldelta);
  const bf16x8 al1 = *(const bf16x8*)(arow + ldelta + 32);
  const bf16x8 al2 = *(const bf16x8*)(arow + ldelta + 64);

  // selection identity: thread = (query selq, chunk selch)
  const int selq = lane;
  const int selch = w;
  const float sqi = sqb[n0 + selq];

  float vals[M_]; int idxs[M_];
  #pragma unroll
  for (int i = 0; i < M_; ++i) { vals[i] = -FLT_MAX; idxs[i] = 0; }

  for (int jt = 0; jt < 64; ++jt) {
    const int jt64 = jt * 64;
    // ---- MFMA phase: this wave's 16q x 64j x K=288 ----
    const ushort* jr0 = hb + (size_t)(jt64 + fm) * 96 + fg * 8;
    const ushort* jr1 = jr0 + 16 * 96;
    const ushort* jr2 = jr0 + 32 * 96;
    const ushort* jr3 = jr0 + 48 * 96;
    f32x4 c0 = {0.f, 0.f, 0.f, 0.f}, c1 = c0, c2 = c0, c3 = c0;
    // segments 0+1 fused: B = h, A = h then l (reuses B frags)
    #pragma unroll
    for (int sl = 0; sl < 3; ++sl) {
      const bf16x8 aH = sl == 0 ? ah0 : sl == 1 ? ah1 : ah2;
      const bf16x8 aL = sl == 0 ? al0 : sl == 1 ? al1 : al2;
      bf16x8 b0 = *(const bf16x8*)(jr0 + sl * 32);
      bf16x8 b1 = *(const bf16x8*)(jr1 + sl * 32);
      bf16x8 b2 = *(const bf16x8*)(jr2 + sl * 32);
      bf16x8 b3 = *(const bf16x8*)(jr3 + sl * 32);
      c0 = MFMA16(aH, b0, c0); c0 = MFMA16(aL, b0, c0);
      c1 = MFMA16(aH, b1, c1); c1 = MFMA16(aL, b1, c1);
      c2 = MFMA16(aH, b2, c2); c2 = MFMA16(aL, b2, c2);
      c3 = MFMA16(aH, b3, c3); c3 = MFMA16(aL, b3, c3);
      __builtin_amdgcn_sched_barrier(0);
    }
    // segment 2: B = l, A = h
    #pragma unroll
    for (int sl = 0; sl < 3; ++sl) {
      const bf16x8 aH = sl == 0 ? ah0 : sl == 1 ? ah1 : ah2;
      bf16x8 b0 = *(const bf16x8*)(jr0 + ldelta + sl * 32);
      bf16x8 b1 = *(const bf16x8*)(jr1 + ldelta + sl * 32);
      bf16x8 b2 = *(const bf16x8*)(jr2 + ldelta + sl * 32);
      bf16x8 b3 = *(const bf16x8*)(jr3 + ldelta + sl * 32);
      c0 = MFMA16(aH, b0, c0);
      c1 = MFMA16(aH, b1, c1);
      c2 = MFMA16(aH, b2, c2);
      c3 = MFMA16(aH, b3, c3);
      __builtin_amdgcn_sched_barrier(0);
    }
    // D layout (m89): row = fg*4 + r (q-local), col = fm (j-local)
    const int buf = jt & 1;
    #pragma unroll
    for (int jb = 0; jb < 4; ++jb) {
      const f32x4 cc = jb == 0 ? c0 : jb == 1 ? c1 : jb == 2 ? c2 : c3;
      #pragma unroll
      for (int r = 0; r < 4; ++r)
        sS[buf][w * 16 + fg * 4 + r][jb * 16 + fm] = cc[r];
    }
    __syncthreads();   // single barrier/tile: dbuf sS makes it sufficient
    // ---- selection phase: 16 scores per thread ----
    #pragma unroll 1
    for (int jj = 0; jj < 16; ++jj) {
      const int j = jt64 + selch * 16 + jj;
      float sc = sS[buf][selq][selch * 16 + jj];
      float neg = 2.f * sc - sqi - sqb[j];
      if (neg > vals[M_ - 1]) {          // strict >: earlier index wins
        float v = neg; int id = j;
        #pragma unroll
        for (int i = 0; i < M_; ++i) {
          if (v > vals[i]) {
            float tv = vals[i]; vals[i] = v; v = tv;
            int ti = idxs[i]; idxs[i] = id; id = ti;
          }
        }
      }
    }
  }

  // ---- fp64 exact re-score of the M_ candidates -> sorted top-16 ----
  const double dsqi = sqd[bN + n0 + selq];
  const double* sqdb = sqd + bN;
  const float* yTb = yT + (size_t)bN * 96;
  const float4* q4p = (const float4*)(yTb + (size_t)(n0 + selq) * 96);
  double bd[16]; int bix[16];
  #pragma unroll
  for (int i = 0; i < 16; ++i) { bd[i] = -DBL_MAX; bix[i] = INT_MAX; }
  #pragma unroll 1
  for (int r = 0; r < M_; ++r) {
    const int j = idxs[r];
    const float4* p4p = (const float4*)(yTb + (size_t)j * 96);
    double a0 = 0.0, a1 = 0.0, a2 = 0.0, a3 = 0.0;
    #pragma unroll 4
    for (int m = 0; m < 24; ++m) {
      float4 qm = q4p[m], pm = p4p[m];
      a0 += (double)qm.x * (double)pm.x;
      a1 += (double)qm.y * (double)pm.y;
      a2 += (double)qm.z * (double)pm.z;
      a3 += (double)qm.w * (double)pm.w;
    }
    double dneg = 2.0 * ((a0 + a1) + (a2 + a3)) - dsqi - sqdb[j];
    if (dneg > bd[15] || (dneg == bd[15] && j < bix[15])) {
      double v = dneg; int id = j;
      #pragma unroll
      for (int i = 0; i < 16; ++i) {
        if (v > bd[i] || (v == bd[i] && id < bix[i])) {
          double tv = bd[i]; bd[i] = v; v = tv;
          int ti = bix[i]; bix[i] = id; id = ti;
        }
      }
    }
  }
  __syncthreads();   // all sS reads done before union reuse

  #pragma unroll
  for (int r = 0; r < 16; ++r) { mvd[selch][selq][r] = bd[r]; mi[selch][selq][r] = bix[r]; }
  mvd[selch][selq][16] = -DBL_MAX; mi[selch][selq][16] = INT_MAX;   // sentinel
  __syncthreads();

  if (t < 64) {
    int p0 = 0, p1 = 0, p2 = 0, p3 = 0;
    int* outp = knn + ((size_t)bN + n0 + t) * 16;
    for (int r = 0; r < 16; ++r) {
      double bv = mvd[0][t][p0]; int bi2 = mi[0][t][p0]; int bc = 0;
      { double v = mvd[1][t][p1]; int id = mi[1][t][p1];
        if (v > bv || (v == bv && id < bi2)) { bv = v; bi2 = id; bc = 1; } }
      { double v = mvd[2][t][p2]; int id = mi[2][t][p2];
        if (v > bv || (v == bv && id < bi2)) { bv = v; bi2 = id; bc = 2; } }
      { double v = mvd[3][t][p3]; int id = mi[3][t][p3];
        if (v > bv || (v == bv && id < bi2)) { bv = v; bi2 = id; bc = 3; } }
      outp[r] = bi2;
      p0 += (bc == 0); p1 += (bc == 1); p2 += (bc == 2); p3 += (bc == 3);
    }
  }
}

__device__ __forceinline__ float f4e(const float4& v, int i) {
  return i == 0 ? v.x : i == 1 ? v.y : i == 2 ? v.z : v.w;
}

// Fused main: 8 queries/block, 32 threads/query (thread = channel),
// 2 queries per wave. Weights transposed-staged in LDS as float4 [c4][o]
// (lane-contiguous b128). Neighbors read as wave-broadcast global float4
// from yT (L2/L3-resident). No cross-channel exchange thanks to E = D@W.
__global__ __launch_bounds__(256) void kC_main(
    const float* __restrict__ x, const float* __restrict__ yT,
    const int* __restrict__ knn,
    const float* __restrict__ Wq, const float* __restrict__ Eq,
    const float* __restrict__ Wk, const float* __restrict__ Ek,
    const float* __restrict__ Wv, const float* __restrict__ Ev,
    float* __restrict__ out) {
  __shared__ float4 sWq[8 * 32], sEq[8 * 32];
  __shared__ float4 sWk[16 * 32], sEk[16 * 32], sWv[16 * 32], sEv[16 * 32];
  __shared__ float sOut[8][97];

  int t = threadIdx.x;
  {
    int e = t;
    int c4 = e >> 5, o = e & 31;
    sWq[e] = ((const float4*)(Wq + o * 32))[c4];
    sEq[e] = ((const float4*)(Eq + o * 32))[c4];
  }
  for (int e = t; e < 512; e += 256) {
    int c4 = e >> 5, o = e & 31;
    sWk[e] = ((const float4*)(Wk + o * 64))[c4];
    sEk[e] = ((const float4*)(Ek + o * 64))[c4];
    sWv[e] = ((const float4*)(Wv + o * 64))[c4];
    sEv[e] = ((const float4*)(Ev + o * 64))[c4];
  }
  __syncthreads();

  int q = t >> 5, o = t & 31;
  int bno = blockIdx.x;
  int b = bno >> 9;
  int n = ((bno & 511) << 3) + q;
  int h = o >> 4, kk_mine = o & 15;

  // ---- Qx ----
  const float* xb = x + (size_t)b * 96 * N_ + n;
  float pq[3] = {0, 0, 0}, dq[3] = {0, 0, 0};
  #pragma unroll
  for (int c4 = 0; c4 < 8; ++c4) {
    float4 wq = sWq[c4 * 32 + o], eq = sEq[c4 * 32 + o];
    #pragma unroll
    for (int i = 0; i < 4; ++i) {
      int c = c4 * 4 + i;
      float w = f4e(wq, i), e2 = f4e(eq, i);
      #pragma unroll
      for (int d = 0; d < 3; ++d) {
        float xv = xb[(size_t)(c * 3 + d) * N_];
        pq[d] = fmaf(w, xv, pq[d]);
        dq[d] = fmaf(e2, xv, dq[d]);
      }
    }
  }
  float Qx[3];
  {
    float dot = pq[0] * dq[0] + pq[1] * dq[1] + pq[2] * dq[2];
    float dsq = dq[0] * dq[0] + dq[1] * dq[1] + dq[2] * dq[2] + 1e-6f;
    float r = dot / dsq;
    float qv[3];
    #pragma unroll
    for (int d = 0; d < 3; ++d) {
      float pn = pq[d] - r * dq[d];
      qv[d] = 0.2f * pq[d] + 0.8f * (dot >= 0.f ? pq[d] : pn);
    }
    float nn = sqrtf(qv[0] * qv[0] + qv[1] * qv[1] + qv[2] * qv[2]);
    float nch2 = nn * nn;
    #pragma unroll
    for (int m = 1; m <= 16; m <<= 1) nch2 += __shfl_xor(nch2, m, 32);
    float s = (nn / fmaxf(sqrtf(nch2), 1e-12f)) / fmaxf(nn, 1e-12f);
    #pragma unroll
    for (int d = 0; d < 3; ++d) Qx[d] = qv[d] * s;
  }

  const float* ctr = yT + ((size_t)b * N_ + n) * 96;
  const int* kidx = knn + ((size_t)b * N_ + n) * 16;

  // ---- K pass ----
  float pck[3] = {0, 0, 0}, dck[3] = {0, 0, 0};
  #pragma unroll
  for (int c4 = 0; c4 < 8; ++c4) {
    float4 wlo = sWk[c4 * 32 + o], whi = sWk[(c4 + 8) * 32 + o];
    float4 elo = sEk[c4 * 32 + o], ehi = sEk[(c4 + 8) * 32 + o];
    float4 c0 = ((const float4*)ctr)[c4 * 3 + 0];
    float4 c1 = ((const float4*)ctr)[c4 * 3 + 1];
    float4 c2 = ((const float4*)ctr)[c4 * 3 + 2];
    float cv[12] = {c0.x, c0.y, c0.z, c0.w, c1.x, c1.y, c1.z, c1.w, c2.x, c2.y, c2.z, c2.w};
    #pragma unroll
    for (int v = 0; v < 12; ++v) {
      int cl = v / 3, d = v % 3;
      pck[d] = fmaf(f4e(whi, cl) - f4e(wlo, cl), cv[v], pck[d]);
      dck[d] = fmaf(f4e(ehi, cl) - f4e(elo, cl), cv[v], dck[d]);
    }
  }

  float myscore = 0.f;
  #pragma unroll 1
  for (int k = 0; k < 16; ++k) {
    int jn = kidx[k];
    const float* nb = yT + ((size_t)b * N_ + jn) * 96;
    float p[3] = {pck[0], pck[1], pck[2]}, dd[3] = {dck[0], dck[1], dck[2]};
    #pragma unroll
    for (int c4 = 0; c4 < 8; ++c4) {
      float4 w = sWk[c4 * 32 + o], e = sEk[c4 * 32 + o];
      float4 n0 = ((const float4*)nb)[c4 * 3 + 0];
      float4 n1 = ((const float4*)nb)[c4 * 3 + 1];
      float4 n2 = ((const float4*)nb)[c4 * 3 + 2];
      float nv[12] = {n0.x, n0.y, n0.z, n0.w, n1.x, n1.y, n1.z, n1.w, n2.x, n2.y, n2.z, n2.w};
      #pragma unroll
      for (int v = 0; v < 12; ++v) {
        int cl = v / 3, d = v % 3;
        p[d]  = fmaf(f4e(w, cl), nv[v], p[d]);
        dd[d] = fmaf(f4e(e, cl), nv[v], dd[d]);
      }
    }
    float dot = p[0] * dd[0] + p[1] * dd[1] + p[2] * dd[2];
    float dsq = dd[0] * dd[0] + dd[1] * dd[1] + dd[2] * dd[2] + 1e-6f;
    float r = dot / dsq;
    float ky[3];
    #pragma unroll
    for (int d = 0; d < 3; ++d) {
      float pn = p[d] - r * dd[d];
      ky[d] = 0.2f * p[d] + 0.8f * (dot >= 0.f ? p[d] : pn);
    }
    float nn = sqrtf(ky[0] * ky[0] + ky[1] * ky[1] + ky[2] * ky[2]);
    float nch2 = nn * nn;
    #pragma unroll
    for (int m = 1; m <= 16; m <<= 1) nch2 += __shfl_xor(nch2, m, 32);
    float s = (1.f / fmaxf(sqrtf(nch2), 1e-12f)) * (nn / fmaxf(nn, 1e-12f));
    float qk = (ky[0] * Qx[0] + ky[1] * Qx[1] + ky[2] * Qx[2]) * s;
    #pragma unroll
    for (int m = 1; m <= 8; m <<= 1) qk += __shfl_xor(qk, m, 32);
    float score = qk * 0.14433756729740643f;   // 1/sqrt(48)
    if (kk_mine == k) myscore = score;
  }

  // ---- softmax ----
  float att_mine;
  {
    float mx = myscore;
    #pragma unroll
    for (int m = 1; m <= 8; m <<= 1) mx = fmaxf(mx, __shfl_xor(mx, m, 32));
    float ex = expf(myscore - mx);
    float ss = ex;
    #pragma unroll
    for (int m = 1; m <= 8; m <<= 1) ss += __shfl_xor(ss, m, 32);
    att_mine = ex / ss;
  }

  // ---- V pass ----
  float pcv[3] = {0, 0, 0}, dcv[3] = {0, 0, 0};
  #pragma unroll
  for (int c4 = 0; c4 < 8; ++c4) {
    float4 wlo = sWv[c4 * 32 + o], whi = sWv[(c4 + 8) * 32 + o];
    float4 elo = sEv[c4 * 32 + o], ehi = sEv[(c4 + 8) * 32 + o];
    float4 c0 = ((const float4*)ctr)[c4 * 3 + 0];
    float4 c1 = ((const float4*)ctr)[c4 * 3 + 1];
    float4 c2 = ((const float4*)ctr)[c4 * 3 + 2];
    float cv[12] = {c0.x, c0.y, c0.z, c0.w, c1.x, c1.y, c1.z, c1.w, c2.x, c2.y, c2.z, c2.w};
    #pragma unroll
    for (int v = 0; v < 12; ++v) {
      int cl = v / 3, d = v % 3;
      pcv[d] = fmaf(f4e(whi, cl) - f4e(wlo, cl), cv[v], pcv[d]);
      dcv[d] = fmaf(f4e(ehi, cl) - f4e(elo, cl), cv[v], dcv[d]);
    }
  }
  float acc[3] = {0, 0, 0};
  #pragma unroll 1
  for (int k = 0; k < 16; ++k) {
    int jn = kidx[k];
    const float* nb = yT + ((size_t)b * N_ + jn) * 96;
    float p[3] = {pcv[0], pcv[1], pcv[2]}, dd[3] = {dcv[0], dcv[1], dcv[2]};
    #pragma unroll
    for (int c4 = 0; c4 < 8; ++c4) {
      float4 w = sWv[c4 * 32 + o], e = sEv[c4 * 32 + o];
      float4 n0 = ((const float4*)nb)[c4 * 3 + 0];
      float4 n1 = ((const float4*)nb)[c4 * 3 + 1];
      float4 n2 = ((const float4*)nb)[c4 * 3 + 2];
      float nv[12] = {n0.x, n0.y, n0.z, n0.w, n1.x, n1.y, n1.z, n1.w, n2.x, n2.y, n2.z, n2.w};
      #pragma unroll
      for (int v = 0; v < 12; ++v) {
        int cl = v / 3, d = v % 3;
        p[d]  = fmaf(f4e(w, cl), nv[v], p[d]);
        dd[d] = fmaf(f4e(e, cl), nv[v], dd[d]);
      }
    }
    float dot = p[0] * dd[0] + p[1] * dd[1] + p[2] * dd[2];
    float dsq = dd[0] * dd[0] + dd[1] * dd[1] + dd[2] * dd[2] + 1e-6f;
    float r = dot / dsq;
    float attk = __shfl(att_mine, h * 16 + k, 32);
    #pragma unroll
    for (int d = 0; d < 3; ++d) {
      float pn = p[d] - r * dd[d];
      float vy = 0.2f * p[d] + 0.8f * (dot >= 0.f ? p[d] : pn);
      acc[d] = fmaf(attk, vy, acc[d]);
    }
  }

  // ---- output ----
  #pragma unroll
  for (int d = 0; d < 3; ++d) sOut[q][o * 3 + d] = acc[d];
  __syncthreads();
  int nl = t & 7;
  int n_out = ((bno & 511) << 3) + nl;
  #pragma unroll
  for (int it = 0; it < 3; ++it) {
    int od = it * 32 + (t >> 3);
    size_t a = (size_t)b * 96 * N_ + (size_t)od * N_ + n_out;
    out[a] = x[a] + sOut[nl][od];
  }
}

extern "C" void kernel_launch(void* const* d_in, const int* in_sizes, int n_in,
                              void* d_out, int out_size, void* d_ws, size_t ws_size,
                              hipStream_t stream) {
  const float* x  = (const float*)d_in[0];
  const float* y  = (const float*)d_in[1];
  const float* Wq = (const float*)d_in[2];
  const float* Dq = (const float*)d_in[3];
  const float* Wk = (const float*)d_in[4];
  const float* Dk = (const float*)d_in[5];
  const float* Wv = (const float*)d_in[6];
  const float* Dv = (const float*)d_in[7];
  float* out = (float*)d_out;

  char* wsb = (char*)d_ws;
  float*  yT  = (float*)wsb;                                   // 12,582,912 B
  double* sqd = (double*)(wsb + 12582912);                     //    262,144 B
  float*  sq  = (float*)(wsb + 12845056);                      //    131,072 B
  int*    knn = (int*)(wsb + 12976128);                        //  2,097,152 B
  ushort* hB  = (ushort*)(wsb + 15073280);                     //  6,291,456 B
  ushort* lB  = (ushort*)(wsb + 21364736);                     //  6,291,456 B
  float*  Ek  = (float*)(wsb + 27656192);                      //      8,192 B
  float*  Ev  = Ek + 2048;
  float*  Eq  = Ev + 2048;

  kE_combine<<<dim3(1), dim3(256), 0, stream>>>(Wk, Dk, Wv, Dv, Wq, Dq, Ek, Ev, Eq);
  kA_transpose<<<dim3(512), dim3(256), 0, stream>>>(y, yT, sq, sqd, hB, lB);
  kB_knn<<<dim3(512), dim3(256), 0, stream>>>(yT, hB, lB, sq, sqd, knn);
  kC_main<<<dim3(4096), dim3(256), 0, stream>>>(x, yT, knn, Wq, Eq, Wk, Ek, Wv, Ev, out);
}